// Round 10
// baseline (182.052 us; speedup 1.0000x reference)
//
#include <hip/hip_runtime.h>
#include <hip/hip_bf16.h>

// ReBASED attention R13: uniform blocks via BQ=64 paired q-tiles (pj, 31-pj).
// R12 post-mortem: 63.5us main, all pipes <40%, occupancy 33.6% == the drain
// model (4 blocks/CU, no backfill, residency declines 4->1 as light tiles
// finish). R10 balanced per-CU SUM (null); the shape itself must change.
// R13: BQ=64 -> tile qt needs exactly qt+1 k-iters; block = pair (31-pj, pj)
// run sequentially = EXACTLY 33 iters for every block. Grid (64,16) = 1024
// uniform blocks = 4/CU, flat 16 waves/CU to the common finish. No fences,
// no backfill reliance. Per-iter wave work halves (mt=1), barriers double,
// but every barrier wait now has 3 other resident blocks to hide behind.
// Kept from R12: bf16 pre-pass (K 16B-group g^=row&7, V^T 8B-group sg^=d&15
// swizzled LDS-images), global_load_lds 16B staging, counted vmcnt(4)
// pipeline, compile-time cur (A/B bodies), z-via-MFMA, uniform-branch causal
// mask (only the diagonal iter), S^T orientation, Q-frags in regs,
// head-per-XCD grid.x, (256,4).

#define SEQ 2048
#define HD  64
#define BQ  64
#define BK  64

typedef __attribute__((ext_vector_type(8))) short bf16x8;
typedef __attribute__((ext_vector_type(4))) short bf16x4;
typedef __attribute__((ext_vector_type(4))) float f32x4;
typedef __attribute__((ext_vector_type(4))) unsigned u32x4;

__device__ inline unsigned packbf(float a, float b) {
    __hip_bfloat162 h = __float22bfloat162_rn(make_float2(a, b));  // a->low, b->high
    union { __hip_bfloat162 h2; unsigned u; } cv; cv.h2 = h; return cv.u;
}

__device__ inline void gload_lds16(const void* g, void* l) {
    __builtin_amdgcn_global_load_lds(
        (const __attribute__((address_space(1))) unsigned*)g,
        (__attribute__((address_space(3))) unsigned*)l, 16, 0, 0);
}

// ---------------- pre-pass: K/V -> bf16 swizzled LDS-image tiles ----------------
// K tile (64x64): kws[tile][r][g'*8..] = K[r][g*8..+7], g' = g ^ (r&7)   (16B groups)
// V tile (64x64): vws[tile][d][sg'*4..] = V[sg*4..+3][d], sg' = sg ^ (d&15) (8B groups)
__global__ __launch_bounds__(256)
void convert_kv_kernel(const float* __restrict__ kg, const float* __restrict__ vg,
                       unsigned short* __restrict__ kws, unsigned short* __restrict__ vws) {
    __shared__ unsigned short vt[64][66];   // V tile bf16, padded (2-way max on reads)

    const int head = blockIdx.x;
    const int kt   = blockIdx.y;
    const int t    = threadIdx.x;
    const size_t gbase = (size_t)head * SEQ * HD + (size_t)kt * BK * HD;
    unsigned short* ktile = kws + gbase;
    unsigned short* vtile = vws + gbase;

    // ---- K: coalesced read, swizzled 16B-group write (16B stores) ----
    {
        const int r = t >> 2, qr = t & 3;
        #pragma unroll
        for (int gg = 0; gg < 2; ++gg) {
            const int g = qr * 2 + gg;
            float4 a = *(const float4*)(kg + gbase + r * HD + g * 8);
            float4 b = *(const float4*)(kg + gbase + r * HD + g * 8 + 4);
            u32x4 pkd;
            pkd[0] = packbf(a.x, a.y); pkd[1] = packbf(a.z, a.w);
            pkd[2] = packbf(b.x, b.y); pkd[3] = packbf(b.z, b.w);
            *(u32x4*)(ktile + r * 64 + ((g ^ (r & 7)) << 3)) = pkd;
        }
    }

    // ---- V: coalesced read -> bf16 LDS -> transposed read -> contiguous write ----
    {
        const int vrow = t >> 5;           // 0..7
        const int vd2  = (t & 31) * 2;     // even d
        #pragma unroll
        for (int p = 0; p < 8; ++p) {
            const int row = p * 8 + vrow;
            float2 v = *(const float2*)(vg + gbase + row * HD + vd2);
            *(unsigned*)&vt[row][vd2] = packbf(v.x, v.y);
        }
    }
    __syncthreads();
    {
        const int sg = t & 15;             // logical 8B group (4 rows)
        const int d0 = t >> 4;             // 0..15
        #pragma unroll
        for (int p = 0; p < 4; ++p) {
            const int d = p * 16 + d0;
            unsigned lo = (unsigned)vt[sg * 4 + 0][d] | ((unsigned)vt[sg * 4 + 1][d] << 16);
            unsigned hi = (unsigned)vt[sg * 4 + 2][d] | ((unsigned)vt[sg * 4 + 3][d] << 16);
            *(uint2*)(vtile + d * 64 + ((sg ^ (d & 15)) << 2)) = make_uint2(lo, hi);
        }
    }
}

// ---------------- main kernel ----------------
__global__ __launch_bounds__(256, 4)
void rebased_r13_kernel(const float* __restrict__ qg,
                        const unsigned short* __restrict__ kws,
                        const unsigned short* __restrict__ vws,
                        float* __restrict__ og) {
    __shared__ __align__(16) unsigned short Ks[2][BK][HD];    // swizzled image, 8KB each
    __shared__ __align__(16) unsigned short Vst[2][HD][BK];   // swizzled V^T image

    const int t    = threadIdx.x;
    const int lane = t & 63;
    const int w    = t >> 6;        // wave: q-rows [w*16, w*16+16) of the 64-row tile
    const int li   = lane & 15;
    const int qd   = lane >> 4;     // quad
    const int head = blockIdx.x;    // id%8 == head%8 -> head pinned to one XCD
    const int pj   = blockIdx.y;    // pair (31-pj, pj): every block = 33 k-iters
    const size_t base = (size_t)head * SEQ * HD;

    // ---- DMA staging: wave w fills bytes [w*1024 + lane*16) of each 4KB half ----
    const int woff = w * 1024;
    const int goff = woff + lane * 16;
    #define STAGE(b, kt2)                                                          \
    {                                                                              \
        const char* ksrc = (const char*)(kws + base + (size_t)(kt2) * BK * HD);    \
        const char* vsrc = (const char*)(vws + base + (size_t)(kt2) * BK * HD);    \
        char* kdst = (char*)&Ks[b][0][0];                                          \
        char* vdst = (char*)&Vst[b][0][0];                                         \
        gload_lds16(ksrc + goff,        kdst + woff);                              \
        gload_lds16(ksrc + goff + 4096, kdst + woff + 4096);                       \
        gload_lds16(vsrc + goff,        vdst + woff);                              \
        gload_lds16(vsrc + goff + 4096, vdst + woff + 4096);                       \
    }

    // pipeline barriers: counted vmcnt, single-asm so nothing crosses
    #define WAITBAR4 asm volatile("s_waitcnt vmcnt(4)\n\ts_barrier" ::: "memory")
    #define WAITBAR0 asm volatile("s_waitcnt vmcnt(0)\n\ts_barrier" ::: "memory")
    #define ENDBAR   asm volatile("s_waitcnt lgkmcnt(0)\n\ts_barrier" ::: "memory")

    bf16x4 onesb;
    { union { unsigned short us[4]; bf16x4 v; } o;
      o.us[0] = o.us[1] = o.us[2] = o.us[3] = 0x3F80; onesb = o.v; }

    #define COMPUTE(curq, ktq)                                                         \
    {                                                                                  \
        const bool needmask = ((ktq) * BK + 63 > qrow_min);                            \
        _Pragma("unroll")                                                              \
        for (int h = 0; h < 2; ++h) {                                                  \
            f32x4 stt[2];                                                              \
            stt[0] = (f32x4){0.f, 0.f, 0.f, 0.f};                                      \
            stt[1] = (f32x4){0.f, 0.f, 0.f, 0.f};                                      \
            _Pragma("unroll")                                                          \
            for (int ks = 0; ks < 2; ++ks) {                                           \
                bf16x8 kf[2];                                                          \
                _Pragma("unroll")                                                      \
                for (int n2 = 0; n2 < 2; ++n2) {                                       \
                    const int row = (h * 2 + n2) * 16 + li;                            \
                    const int grp = ((ks * 4 + qd) ^ (li & 7)) << 3;                   \
                    kf[n2] = *(const bf16x8*)&Ks[curq][row][grp];                      \
                }                                                                      \
                _Pragma("unroll")                                                      \
                for (int n2 = 0; n2 < 2; ++n2)                                         \
                    stt[n2] = __builtin_amdgcn_mfma_f32_16x16x32_bf16(                 \
                        kf[n2], qf[ks], stt[n2], 0, 0, 0);                             \
            }                                                                          \
            /* causal mask: wave-uniform branch, taken only on the diagonal iter */    \
            if (needmask) {                                                            \
                const int qrow = qrow_min + li;                                        \
                _Pragma("unroll")                                                      \
                for (int n2 = 0; n2 < 2; ++n2) {                                       \
                    const int kcb = (ktq) * BK + (h * 2 + n2) * 16 + qd * 4;           \
                    _Pragma("unroll")                                                  \
                    for (int r = 0; r < 4; ++r)                                        \
                        if (kcb + r > qrow) stt[n2][r] = 0.f;                          \
                }                                                                      \
            }                                                                          \
            unsigned pk[2][2];                                                         \
            _Pragma("unroll")                                                          \
            for (int n2 = 0; n2 < 2; ++n2) {                                           \
                float p0 = stt[n2][0] * stt[n2][0];                                    \
                float p1 = stt[n2][1] * stt[n2][1];                                    \
                float p2 = stt[n2][2] * stt[n2][2];                                    \
                float p3 = stt[n2][3] * stt[n2][3];                                    \
                pk[n2][0] = packbf(p0, p1);                                            \
                pk[n2][1] = packbf(p2, p3);                                            \
            }                                                                          \
            _Pragma("unroll")                                                          \
            for (int s2 = 0; s2 < 2; ++s2) {                                           \
                bf16x4 av;                                                             \
                { union { unsigned u[2]; bf16x4 v; } cv;                               \
                  cv.u[0] = pk[s2][0]; cv.u[1] = pk[s2][1]; av = cv.v; }               \
                zacc = __builtin_amdgcn_mfma_f32_16x16x16bf16_1k(                      \
                    av, onesb, zacc, 0, 0, 0);                                         \
                const int sg = (h * 2 + s2) * 4 + qd;                                  \
                _Pragma("unroll")                                                      \
                for (int nd = 0; nd < 4; ++nd) {                                       \
                    const int d = nd * 16 + li;                                        \
                    bf16x4 vf = *(const bf16x4*)&Vst[curq][d][(sg ^ li) << 2];         \
                    oacc[nd] = __builtin_amdgcn_mfma_f32_16x16x16bf16_1k(              \
                        av, vf, oacc[nd], 0, 0, 0);                                    \
                }                                                                      \
            }                                                                          \
        }                                                                              \
    }

    #pragma unroll
    for (int seg = 0; seg < 2; ++seg) {
        const int qt = seg ? pj : (31 - pj);   // heavy tile first
        const int niters = qt + 1;             // k-tiles 0..qt (BQ=64)
        const int qrow_min = qt * BQ + w * 16;

        // ---- Q fragments straight to registers (per-wave-row private; scaled) ----
        bf16x8 qf[2];   // [ks]
        {
            const float* qrow = qg + base + (size_t)(qrow_min + li) * HD;
            #pragma unroll
            for (int ks = 0; ks < 2; ++ks) {
                float4 a = *(const float4*)(qrow + ks * 32 + qd * 8);
                float4 b = *(const float4*)(qrow + ks * 32 + qd * 8 + 4);
                union { unsigned u[4]; bf16x8 v; } cv;
                cv.u[0] = packbf(a.x * 0.125f, a.y * 0.125f);
                cv.u[1] = packbf(a.z * 0.125f, a.w * 0.125f);
                cv.u[2] = packbf(b.x * 0.125f, b.y * 0.125f);
                cv.u[3] = packbf(b.z * 0.125f, b.w * 0.125f);
                qf[ks] = cv.v;
            }
        }

        f32x4 oacc[4];
        f32x4 zacc = (f32x4){0.f, 0.f, 0.f, 0.f};
        #pragma unroll
        for (int nd = 0; nd < 4; ++nd) oacc[nd] = (f32x4){0.f, 0.f, 0.f, 0.f};

        // seg1: drain seg0's LDS reads before re-staging buf0 (vmcnt already 0)
        if (seg) ENDBAR;

        // ---- k-loop: A/B bodies (compile-time cur), counted vmcnt, any parity ----
        STAGE(0, 0);
        for (int i = 0; ; i += 2) {
            const int ktA = i;
            const bool haveB = (i + 1 < niters);
            if (haveB) { STAGE(1, ktA + 1); WAITBAR4; } else { WAITBAR0; }
            COMPUTE(0, ktA);
            if (!haveB) break;
            ENDBAR;

            const int ktB = i + 1;
            const bool haveC = (i + 2 < niters);
            if (haveC) { STAGE(0, ktB + 1); WAITBAR4; } else { WAITBAR0; }
            COMPUTE(1, ktB);
            if (!haveC) break;
            ENDBAR;
        }

        // ---- epilogue: zacc C-layout == oacc -> local divide, no shuffles ----
        float* odst = og + base + (size_t)qt * BQ * HD;
        #pragma unroll
        for (int r = 0; r < 4; ++r) {
            float inv = 1.f / (zacc[r] + 1e-6f);
            int row = w * 16 + qd * 4 + r;
            #pragma unroll
            for (int nd = 0; nd < 4; ++nd)
                odst[row * HD + nd * 16 + li] = oacc[nd][r] * inv;
        }
    }
}

extern "C" void kernel_launch(void* const* d_in, const int* in_sizes, int n_in,
                              void* d_out, int out_size, void* d_ws, size_t ws_size,
                              hipStream_t stream) {
    const float* q = (const float*)d_in[0];
    const float* k = (const float*)d_in[1];
    const float* v = (const float*)d_in[2];
    float* out = (float*)d_out;

    unsigned short* kws = (unsigned short*)d_ws;
    unsigned short* vws = kws + (size_t)64 * SEQ * HD;   // +16MB; total ws use 32MB

    dim3 cgrid(64, 32);   // (head, k-tile)
    convert_kv_kernel<<<cgrid, dim3(256), 0, stream>>>(k, v, kws, vws);

    dim3 grid(64, 16);    // x=head (XCD affinity); y=pj -> uniform 33-iter blocks
    rebased_r13_kernel<<<grid, dim3(256), 0, stream>>>(q, kws, vws, out);
}

// Round 11
// 177.888 us; speedup vs baseline: 1.0234x; 1.0234x over previous
//
#include <hip/hip_runtime.h>
#include <hip/hip_bf16.h>

// ReBASED attention R14: R12 body with ONE barrier per k-iteration.
// R13 post-mortem: uniform blocks regressed (halved mt kept LDS reads/wave
// constant but halved MFMA per read; barriers doubled). Occupancy counter
// identical (33.5) across totally different shapes -> metric unreliable
// (gfx94x fallback formula); stop steering by it. R12 remains best (63.5us).
// R14 theory: pipe-sum (LDS 43k + MFMA 50k + VALU 45k ~= 138k of 152k wall)
// says pipes are SERIALIZED, not capacity-bound; the serializer is 2 barrier
// convoys per iter. The ENDBAR is redundant: every ds_read is consumed by an
// MFMA (data dep) before its wave reaches the next barrier, so barrier N
// already implies "all reads of the old buffer done". Reorder to
//   [vmcnt(0)+s_barrier] -> STAGE(other buf) -> COMPUTE(cur)
// = one barrier/iter. vmcnt(0) is cheap (waited loads were issued a full
// compute-phase earlier); the fresh STAGE overlaps COMPUTE and is drained at
// the NEXT iteration's wait. Sync events per block: 66 -> 33.
// Kept from R12: bf16 pre-pass (K 16B-group g^=row&7, V^T 8B-group sg^=d&15
// swizzled LDS-images), global_load_lds 16B staging, compile-time cur (A/B
// bodies), z-via-MFMA (zacc C-layout == oacc), uniform-branch causal mask,
// S^T orientation (QK C-layout == PV A-layout), Q-frags in regs, heavy-first
// grid(64,16), head-per-XCD, (256,4), LDS-transpose convert kernel.

#define SEQ 2048
#define HD  64
#define BQ  128
#define BK  64

typedef __attribute__((ext_vector_type(8))) short bf16x8;
typedef __attribute__((ext_vector_type(4))) short bf16x4;
typedef __attribute__((ext_vector_type(4))) float f32x4;
typedef __attribute__((ext_vector_type(4))) unsigned u32x4;

__device__ inline unsigned packbf(float a, float b) {
    __hip_bfloat162 h = __float22bfloat162_rn(make_float2(a, b));  // a->low, b->high
    union { __hip_bfloat162 h2; unsigned u; } cv; cv.h2 = h; return cv.u;
}

__device__ inline void gload_lds16(const void* g, void* l) {
    __builtin_amdgcn_global_load_lds(
        (const __attribute__((address_space(1))) unsigned*)g,
        (__attribute__((address_space(3))) unsigned*)l, 16, 0, 0);
}

// ---------------- pre-pass: K/V -> bf16 swizzled LDS-image tiles ----------------
// K tile (64x64): kws[tile][r][g'*8..] = K[r][g*8..+7], g' = g ^ (r&7)   (16B groups)
// V tile (64x64): vws[tile][d][sg'*4..] = V[sg*4..+3][d], sg' = sg ^ (d&15) (8B groups)
__global__ __launch_bounds__(256)
void convert_kv_kernel(const float* __restrict__ kg, const float* __restrict__ vg,
                       unsigned short* __restrict__ kws, unsigned short* __restrict__ vws) {
    __shared__ unsigned short vt[64][66];   // V tile bf16, padded (2-way max on reads)

    const int head = blockIdx.x;
    const int kt   = blockIdx.y;
    const int t    = threadIdx.x;
    const size_t gbase = (size_t)head * SEQ * HD + (size_t)kt * BK * HD;
    unsigned short* ktile = kws + gbase;
    unsigned short* vtile = vws + gbase;

    // ---- K: coalesced read, swizzled 16B-group write (16B stores) ----
    {
        const int r = t >> 2, qr = t & 3;
        #pragma unroll
        for (int gg = 0; gg < 2; ++gg) {
            const int g = qr * 2 + gg;
            float4 a = *(const float4*)(kg + gbase + r * HD + g * 8);
            float4 b = *(const float4*)(kg + gbase + r * HD + g * 8 + 4);
            u32x4 pkd;
            pkd[0] = packbf(a.x, a.y); pkd[1] = packbf(a.z, a.w);
            pkd[2] = packbf(b.x, b.y); pkd[3] = packbf(b.z, b.w);
            *(u32x4*)(ktile + r * 64 + ((g ^ (r & 7)) << 3)) = pkd;
        }
    }

    // ---- V: coalesced read -> bf16 LDS -> transposed read -> contiguous write ----
    {
        const int vrow = t >> 5;           // 0..7
        const int vd2  = (t & 31) * 2;     // even d
        #pragma unroll
        for (int p = 0; p < 8; ++p) {
            const int row = p * 8 + vrow;
            float2 v = *(const float2*)(vg + gbase + row * HD + vd2);
            *(unsigned*)&vt[row][vd2] = packbf(v.x, v.y);
        }
    }
    __syncthreads();
    {
        const int sg = t & 15;             // logical 8B group (4 rows)
        const int d0 = t >> 4;             // 0..15
        #pragma unroll
        for (int p = 0; p < 4; ++p) {
            const int d = p * 16 + d0;
            unsigned lo = (unsigned)vt[sg * 4 + 0][d] | ((unsigned)vt[sg * 4 + 1][d] << 16);
            unsigned hi = (unsigned)vt[sg * 4 + 2][d] | ((unsigned)vt[sg * 4 + 3][d] << 16);
            *(uint2*)(vtile + d * 64 + ((sg ^ (d & 15)) << 2)) = make_uint2(lo, hi);
        }
    }
}

// ---------------- main kernel ----------------
__global__ __launch_bounds__(256, 4)
void rebased_r14_kernel(const float* __restrict__ qg,
                        const unsigned short* __restrict__ kws,
                        const unsigned short* __restrict__ vws,
                        float* __restrict__ og) {
    __shared__ __align__(16) unsigned short Ks[2][BK][HD];    // swizzled image, 8KB each
    __shared__ __align__(16) unsigned short Vst[2][HD][BK];   // swizzled V^T image

    const int t    = threadIdx.x;
    const int lane = t & 63;
    const int w    = t >> 6;        // wave: q-rows [w*32, w*32+32)
    const int li   = lane & 15;
    const int qd   = lane >> 4;     // quad
    const int head = blockIdx.x;    // id%8 == head%8 -> head pinned to one XCD
    const int qt   = 15 - blockIdx.y;  // heavy-first (LPT)
    const int ktmax = 2 * qt + 1;      // odd -> iteration count even
    const size_t base = (size_t)head * SEQ * HD;

    // ---- Q fragments straight to registers (per-wave private; scaled) ----
    bf16x8 qf[2][2];   // [ks][mt]
    {
        const int qrow0 = qt * BQ + w * 32;
        #pragma unroll
        for (int mt = 0; mt < 2; ++mt) {
            const float* qrow = qg + base + (size_t)(qrow0 + mt * 16 + li) * HD;
            #pragma unroll
            for (int ks = 0; ks < 2; ++ks) {
                float4 a = *(const float4*)(qrow + ks * 32 + qd * 8);
                float4 b = *(const float4*)(qrow + ks * 32 + qd * 8 + 4);
                union { unsigned u[4]; bf16x8 v; } cv;
                cv.u[0] = packbf(a.x * 0.125f, a.y * 0.125f);
                cv.u[1] = packbf(a.z * 0.125f, a.w * 0.125f);
                cv.u[2] = packbf(b.x * 0.125f, b.y * 0.125f);
                cv.u[3] = packbf(b.z * 0.125f, b.w * 0.125f);
                qf[ks][mt] = cv.v;
            }
        }
    }

    // ---- DMA staging: wave w fills bytes [w*1024 + lane*16) of each 4KB half ----
    const int woff = w * 1024;
    const int goff = woff + lane * 16;
    #define STAGE(b, kt2)                                                          \
    {                                                                              \
        const char* ksrc = (const char*)(kws + base + (size_t)(kt2) * BK * HD);    \
        const char* vsrc = (const char*)(vws + base + (size_t)(kt2) * BK * HD);    \
        char* kdst = (char*)&Ks[b][0][0];                                          \
        char* vdst = (char*)&Vst[b][0][0];                                         \
        gload_lds16(ksrc + goff,        kdst + woff);                              \
        gload_lds16(ksrc + goff + 4096, kdst + woff + 4096);                       \
        gload_lds16(vsrc + goff,        vdst + woff);                              \
        gload_lds16(vsrc + goff + 4096, vdst + woff + 4096);                       \
    }

    // single sync point per iteration: drain in-flight stage + rendezvous.
    // Loads waited here were issued one full compute-phase ago (cheap);
    // barrier also proves all waves consumed the buffer STAGE will overwrite
    // (ds_reads are consumed by MFMAs before any wave reaches its barrier).
    #define WB0 asm volatile("s_waitcnt vmcnt(0)\n\ts_barrier" ::: "memory")

    f32x4 oacc[2][4];
    f32x4 zacc[2];
    #pragma unroll
    for (int mt = 0; mt < 2; ++mt) {
        zacc[mt] = (f32x4){0.f, 0.f, 0.f, 0.f};
        #pragma unroll
        for (int nd = 0; nd < 4; ++nd) oacc[mt][nd] = (f32x4){0.f, 0.f, 0.f, 0.f};
    }
    bf16x4 onesb;
    { union { unsigned short us[4]; bf16x4 v; } o;
      o.us[0] = o.us[1] = o.us[2] = o.us[3] = 0x3F80; onesb = o.v; }

    const int qrow_min = qt * BQ + w * 32;

    #define COMPUTE(curq, ktq)                                                         \
    {                                                                                  \
        const bool active = ((ktq) * BK <= qrow_min + 31);                             \
        if (active) {                                                                  \
            const bool needmask = ((ktq) * BK + 63 > qrow_min);                        \
            _Pragma("unroll")                                                          \
            for (int h = 0; h < 2; ++h) {                                              \
                f32x4 stt[2][2];                                                       \
                _Pragma("unroll")                                                      \
                for (int n2 = 0; n2 < 2; ++n2)                                         \
                    _Pragma("unroll")                                                  \
                    for (int mt = 0; mt < 2; ++mt)                                     \
                        stt[n2][mt] = (f32x4){0.f, 0.f, 0.f, 0.f};                     \
                _Pragma("unroll")                                                      \
                for (int ks = 0; ks < 2; ++ks) {                                       \
                    bf16x8 kf[2];                                                      \
                    _Pragma("unroll")                                                  \
                    for (int n2 = 0; n2 < 2; ++n2) {                                   \
                        const int row = (h * 2 + n2) * 16 + li;                        \
                        const int grp = ((ks * 4 + qd) ^ (li & 7)) << 3;               \
                        kf[n2] = *(const bf16x8*)&Ks[curq][row][grp];                  \
                    }                                                                  \
                    _Pragma("unroll")                                                  \
                    for (int n2 = 0; n2 < 2; ++n2)                                     \
                        _Pragma("unroll")                                              \
                        for (int mt = 0; mt < 2; ++mt)                                 \
                            stt[n2][mt] = __builtin_amdgcn_mfma_f32_16x16x32_bf16(     \
                                kf[n2], qf[ks][mt], stt[n2][mt], 0, 0, 0);             \
                }                                                                      \
                /* causal mask: wave-uniform branch, taken on <=2 iters per wave */    \
                if (needmask) {                                                        \
                    _Pragma("unroll")                                                  \
                    for (int n2 = 0; n2 < 2; ++n2) {                                   \
                        const int kcb = (ktq) * BK + (h * 2 + n2) * 16 + qd * 4;       \
                        _Pragma("unroll")                                              \
                        for (int mt = 0; mt < 2; ++mt) {                               \
                            const int qrow = qrow_min + mt * 16 + li;                  \
                            _Pragma("unroll")                                          \
                            for (int r = 0; r < 4; ++r)                                \
                                if (kcb + r > qrow) stt[n2][mt][r] = 0.f;              \
                        }                                                              \
                    }                                                                  \
                }                                                                      \
                unsigned pk[2][2][2];                                                  \
                _Pragma("unroll")                                                      \
                for (int n2 = 0; n2 < 2; ++n2) {                                       \
                    _Pragma("unroll")                                                  \
                    for (int mt = 0; mt < 2; ++mt) {                                   \
                        float p[4];                                                    \
                        _Pragma("unroll")                                              \
                        for (int r = 0; r < 4; ++r) {                                  \
                            float s = stt[n2][mt][r];                                  \
                            p[r] = s * s;                                              \
                        }                                                              \
                        pk[n2][mt][0] = packbf(p[0], p[1]);                            \
                        pk[n2][mt][1] = packbf(p[2], p[3]);                            \
                    }                                                                  \
                }                                                                      \
                _Pragma("unroll")                                                      \
                for (int s2 = 0; s2 < 2; ++s2) {                                       \
                    bf16x4 av[2];                                                      \
                    _Pragma("unroll")                                                  \
                    for (int mt = 0; mt < 2; ++mt) {                                   \
                        union { unsigned u[2]; bf16x4 v; } cv;                         \
                        cv.u[0] = pk[s2][mt][0]; cv.u[1] = pk[s2][mt][1];              \
                        av[mt] = cv.v;                                                 \
                    }                                                                  \
                    _Pragma("unroll")                                                  \
                    for (int mt = 0; mt < 2; ++mt)                                     \
                        zacc[mt] = __builtin_amdgcn_mfma_f32_16x16x16bf16_1k(          \
                            av[mt], onesb, zacc[mt], 0, 0, 0);                         \
                    const int sg = (h * 2 + s2) * 4 + qd;                              \
                    _Pragma("unroll")                                                  \
                    for (int nd = 0; nd < 4; ++nd) {                                   \
                        const int d = nd * 16 + li;                                    \
                        bf16x4 vf = *(const bf16x4*)&Vst[curq][d][(sg ^ li) << 2];     \
                        _Pragma("unroll")                                              \
                        for (int mt = 0; mt < 2; ++mt)                                 \
                            oacc[mt][nd] = __builtin_amdgcn_mfma_f32_16x16x16bf16_1k(  \
                                av[mt], vf, oacc[mt][nd], 0, 0, 0);                    \
                    }                                                                  \
                }                                                                      \
            }                                                                          \
        }                                                                              \
    }

    // ---- k-loop: one barrier per iteration.
    // Per iter: [vmcnt(0)+barrier] -> STAGE(other buf, kt+1) -> COMPUTE(cur, kt).
    // The waited loads were issued one compute-phase ago; the fresh STAGE
    // overlaps COMPUTE and is drained at the next iteration's wait.
    STAGE(0, 0);   // prologue: 4 loads in flight
    for (int kt = 0; kt <= ktmax; kt += 2) {
        // body A: cur=0 (kt even; ktmax odd -> kt < ktmax always)
        WB0;
        STAGE(1, kt + 1);
        COMPUTE(0, kt);

        // body B: cur=1
        WB0;
        if (kt + 1 < ktmax) STAGE(0, kt + 2);
        COMPUTE(1, kt + 1);
    }

    // ---- epilogue: zacc has the same C-layout as oacc -> local divide, no shuffles ----
    float* odst = og + base + (size_t)qt * BQ * HD;
    #pragma unroll
    for (int mt = 0; mt < 2; ++mt) {
        #pragma unroll
        for (int r = 0; r < 4; ++r) {
            float inv = 1.f / (zacc[mt][r] + 1e-6f);
            int row = w * 32 + mt * 16 + qd * 4 + r;
            #pragma unroll
            for (int nd = 0; nd < 4; ++nd)
                odst[row * HD + nd * 16 + li] = oacc[mt][nd][r] * inv;
        }
    }
}

extern "C" void kernel_launch(void* const* d_in, const int* in_sizes, int n_in,
                              void* d_out, int out_size, void* d_ws, size_t ws_size,
                              hipStream_t stream) {
    const float* q = (const float*)d_in[0];
    const float* k = (const float*)d_in[1];
    const float* v = (const float*)d_in[2];
    float* out = (float*)d_out;

    unsigned short* kws = (unsigned short*)d_ws;
    unsigned short* vws = kws + (size_t)64 * SEQ * HD;   // +16MB; total ws use 32MB

    dim3 cgrid(64, 32);   // (head, k-tile)
    convert_kv_kernel<<<cgrid, dim3(256), 0, stream>>>(k, v, kws, vws);

    dim3 grid(64, 16);    // x=head (XCD affinity), y: heavy q-tiles first
    rebased_r14_kernel<<<grid, dim3(256), 0, stream>>>(q, kws, vws, out);
}